// Round 1
// baseline (940.333 us; speedup 1.0000x reference)
//
#include <hip/hip_runtime.h>

#define F_IN  500
#define F_HID 20
#define F_OUT 3

// ---------------- degree count ----------------
__global__ void k_degree(const int* __restrict__ dst, float* __restrict__ deg, int E) {
    int i = blockIdx.x * blockDim.x + threadIdx.x;
    if (i < E) atomicAdd(&deg[dst[i]], 1.0f);
}

// ---------------- layer-1 projections: yl = x@W1l, yr = x@W1r ----------------
// thread per row; W reads are wave-uniform -> scalar loads; x via float4.
__global__ void k_gemm1(const float* __restrict__ x,
                        const float* __restrict__ Wl,
                        const float* __restrict__ Wr,
                        float* __restrict__ yl, float* __restrict__ yr, int N) {
    int row = blockIdx.x * blockDim.x + threadIdx.x;
    if (row >= N) return;
    float acc[2 * F_HID];
#pragma unroll
    for (int c = 0; c < 2 * F_HID; ++c) acc[c] = 0.f;

    const float4* xr = (const float4*)(x + (size_t)row * F_IN);
    for (int k4 = 0; k4 < F_IN / 4; ++k4) {
        float4 xv = xr[k4];
        float xs[4] = {xv.x, xv.y, xv.z, xv.w};
#pragma unroll
        for (int j = 0; j < 4; ++j) {
            int k = k4 * 4 + j;
#pragma unroll
            for (int c = 0; c < F_HID; ++c) {
                acc[c]         += xs[j] * Wl[k * F_HID + c];
                acc[F_HID + c] += xs[j] * Wr[k * F_HID + c];
            }
        }
    }
    float4* po = (float4*)(yl + (size_t)row * F_HID);
#pragma unroll
    for (int q = 0; q < F_HID / 4; ++q)
        po[q] = make_float4(acc[4*q], acc[4*q+1], acc[4*q+2], acc[4*q+3]);
    float4* pr = (float4*)(yr + (size_t)row * F_HID);
#pragma unroll
    for (int q = 0; q < F_HID / 4; ++q)
        pr[q] = make_float4(acc[F_HID+4*q], acc[F_HID+4*q+1], acc[F_HID+4*q+2], acc[F_HID+4*q+3]);
}

// ---------------- scatter yl[src] -> agg1[dst], 4 cols per thread ----------------
__global__ void k_scatter1(const int* __restrict__ src, const int* __restrict__ dst,
                           const float* __restrict__ yl, float* __restrict__ agg1, int E) {
    int i = blockIdx.x * blockDim.x + threadIdx.x;
    if (i >= E * 5) return;
    int e = i / 5;
    int cg = i - e * 5;
    int s = src[e], d = dst[e];
    float4 v = *(const float4*)(yl + (size_t)s * F_HID + cg * 4);
    float* base = agg1 + (size_t)d * F_HID + cg * 4;
    atomicAdd(base + 0, v.x);
    atomicAdd(base + 1, v.y);
    atomicAdd(base + 2, v.z);
    atomicAdd(base + 3, v.w);
}

// ---------------- layer1 epilogue + layer2 projections (h stays in regs) ----------------
__global__ void k_layer1(const float* __restrict__ deg,
                         const float* __restrict__ agg1,
                         const float* __restrict__ yr,
                         const float* __restrict__ b1,
                         const float* __restrict__ W2l,
                         const float* __restrict__ W2r,
                         float* __restrict__ zl, float* __restrict__ zr, int N) {
    int n = blockIdx.x * blockDim.x + threadIdx.x;
    if (n >= N) return;
    float di = 1.0f / fmaxf(deg[n], 1.0f);
    float h[F_HID];
    const float4* pa = (const float4*)(agg1 + (size_t)n * F_HID);
    const float4* pr = (const float4*)(yr + (size_t)n * F_HID);
#pragma unroll
    for (int q = 0; q < F_HID / 4; ++q) {
        float4 a = pa[q];
        float4 r = pr[q];
        h[4*q+0] = fmaxf(a.x * di + b1[4*q+0] + r.x, 0.f);
        h[4*q+1] = fmaxf(a.y * di + b1[4*q+1] + r.y, 0.f);
        h[4*q+2] = fmaxf(a.z * di + b1[4*q+2] + r.z, 0.f);
        h[4*q+3] = fmaxf(a.w * di + b1[4*q+3] + r.w, 0.f);
    }
    float zlo[F_OUT] = {0.f, 0.f, 0.f};
    float zro[F_OUT] = {0.f, 0.f, 0.f};
#pragma unroll
    for (int c = 0; c < F_HID; ++c) {
#pragma unroll
        for (int o = 0; o < F_OUT; ++o) {
            zlo[o] += h[c] * W2l[c * F_OUT + o];
            zro[o] += h[c] * W2r[c * F_OUT + o];
        }
    }
#pragma unroll
    for (int o = 0; o < F_OUT; ++o) {
        zl[(size_t)n * F_OUT + o] = zlo[o];
        zr[(size_t)n * F_OUT + o] = zro[o];
    }
}

// ---------------- scatter zl[src] -> agg2[dst] ----------------
__global__ void k_scatter2(const int* __restrict__ src, const int* __restrict__ dst,
                           const float* __restrict__ zl, float* __restrict__ agg2, int E) {
    int e = blockIdx.x * blockDim.x + threadIdx.x;
    if (e >= E) return;
    int s = src[e], d = dst[e];
#pragma unroll
    for (int o = 0; o < F_OUT; ++o)
        atomicAdd(agg2 + (size_t)d * F_OUT + o, zl[(size_t)s * F_OUT + o]);
}

// ---------------- final combine ----------------
__global__ void k_final(const float* __restrict__ deg,
                        const float* __restrict__ agg2,
                        const float* __restrict__ zr,
                        const float* __restrict__ b2,
                        float* __restrict__ out, int N) {
    int n = blockIdx.x * blockDim.x + threadIdx.x;
    if (n >= N) return;
    float di = 1.0f / fmaxf(deg[n], 1.0f);
#pragma unroll
    for (int o = 0; o < F_OUT; ++o)
        out[(size_t)n * F_OUT + o] = agg2[(size_t)n * F_OUT + o] * di + b2[o] + zr[(size_t)n * F_OUT + o];
}

extern "C" void kernel_launch(void* const* d_in, const int* in_sizes, int n_in,
                              void* d_out, int out_size, void* d_ws, size_t ws_size,
                              hipStream_t stream) {
    const float* x   = (const float*)d_in[0];
    const int*   ei  = (const int*)d_in[1];
    const float* W1l = (const float*)d_in[2];
    const float* W1r = (const float*)d_in[3];
    const float* b1  = (const float*)d_in[4];
    const float* W2l = (const float*)d_in[5];
    const float* W2r = (const float*)d_in[6];
    const float* b2  = (const float*)d_in[7];
    float* out = (float*)d_out;

    const int N = in_sizes[0] / F_IN;     // 100000
    const int E = in_sizes[1] / 2;        // 800000
    const int* src = ei;
    const int* dst = ei + E;

    // workspace layout (floats). [deg | agg1 | agg2] contiguous -> one memset.
    float* ws = (float*)d_ws;
    float* deg  = ws;                         // N
    float* agg1 = deg  + N;                   // N*20
    float* agg2 = agg1 + (size_t)N * F_HID;   // N*3
    float* yl   = agg2 + (size_t)N * F_OUT;   // N*20
    float* yr   = yl   + (size_t)N * F_HID;   // N*20
    float* zl   = yr   + (size_t)N * F_HID;   // N*3
    float* zr   = zl   + (size_t)N * F_OUT;   // N*3

    size_t zero_bytes = ((size_t)N * (1 + F_HID + F_OUT)) * sizeof(float);
    hipMemsetAsync(d_ws, 0, zero_bytes, stream);

    const int B = 256;
    k_degree  <<<(E + B - 1) / B, B, 0, stream>>>(dst, deg, E);
    k_gemm1   <<<(N + B - 1) / B, B, 0, stream>>>(x, W1l, W1r, yl, yr, N);
    k_scatter1<<<(E * 5 + B - 1) / B, B, 0, stream>>>(src, dst, yl, agg1, E);
    k_layer1  <<<(N + B - 1) / B, B, 0, stream>>>(deg, agg1, yr, b1, W2l, W2r, zl, zr, N);
    k_scatter2<<<(E + B - 1) / B, B, 0, stream>>>(src, dst, zl, agg2, E);
    k_final   <<<(N + B - 1) / B, B, 0, stream>>>(deg, agg2, zr, b2, out, N);
}

// Round 2
// 556.870 us; speedup vs baseline: 1.6886x; 1.6886x over previous
//
#include <hip/hip_runtime.h>

#define F_IN  500
#define F_HID 20
#define F_OUT 3

// ---------------- int degree count ----------------
__global__ void k_degree(const int* __restrict__ dst, int* __restrict__ deg, int E) {
    int i = blockIdx.x * blockDim.x + threadIdx.x;
    if (i < E) atomicAdd(&deg[dst[i]], 1);
}

// ---------------- scan stage 1: per-block exclusive scan (1024 elems/block) ----------------
__global__ void k_scan_blk(const int* __restrict__ deg, int* __restrict__ rowstart,
                           int* __restrict__ blocksums, int N) {
    __shared__ int lds[256];
    int tid = threadIdx.x;
    int base = blockIdx.x * 1024 + tid * 4;
    int4 v = make_int4(0, 0, 0, 0);
    if (base + 3 < N) {
        v = *(const int4*)(deg + base);
    } else {
        if (base + 0 < N) v.x = deg[base + 0];
        if (base + 1 < N) v.y = deg[base + 1];
        if (base + 2 < N) v.z = deg[base + 2];
        if (base + 3 < N) v.w = deg[base + 3];
    }
    int tsum = v.x + v.y + v.z + v.w;
    lds[tid] = tsum;
    __syncthreads();
    // inclusive scan over 256 thread-sums
    for (int off = 1; off < 256; off <<= 1) {
        int t = (tid >= off) ? lds[tid - off] : 0;
        __syncthreads();
        lds[tid] += t;
        __syncthreads();
    }
    int excl = lds[tid] - tsum;
    if (tid == 255) blocksums[blockIdx.x] = lds[255];
    int r = excl;
    if (base + 0 < N) rowstart[base + 0] = r; r += v.x;
    if (base + 1 < N) rowstart[base + 1] = r; r += v.y;
    if (base + 2 < N) rowstart[base + 2] = r; r += v.z;
    if (base + 3 < N) rowstart[base + 3] = r;
}

// ---------------- scan stage 2: exclusive scan of block sums (NB <= 256) ----------------
__global__ void k_scan_sums(int* __restrict__ blocksums, int NB) {
    __shared__ int lds[256];
    int tid = threadIdx.x;
    int v = (tid < NB) ? blocksums[tid] : 0;
    lds[tid] = v;
    __syncthreads();
    for (int off = 1; off < 256; off <<= 1) {
        int t = (tid >= off) ? lds[tid - off] : 0;
        __syncthreads();
        lds[tid] += t;
        __syncthreads();
    }
    if (tid < NB) blocksums[tid] = lds[tid] - v;
}

// ---------------- scan stage 3: add block offsets ----------------
__global__ void k_scan_add(int* __restrict__ rowstart, const int* __restrict__ blocksums, int N) {
    int i = blockIdx.x * blockDim.x + threadIdx.x;
    if (i < N) rowstart[i] += blocksums[i >> 10];
}

// ---------------- CSR fill: after this, rowstart[n] == row END ----------------
__global__ void k_fill(const int* __restrict__ src, const int* __restrict__ dst,
                       int* __restrict__ rowstart, int* __restrict__ csr, int E) {
    int e = blockIdx.x * blockDim.x + threadIdx.x;
    if (e >= E) return;
    int pos = atomicAdd(&rowstart[dst[e]], 1);
    csr[pos] = src[e];
}

// ---------------- layer-1 projections: yl = x@W1l, yr = x@W1r ----------------
__global__ void k_gemm1(const float* __restrict__ x,
                        const float* __restrict__ Wl,
                        const float* __restrict__ Wr,
                        float* __restrict__ yl, float* __restrict__ yr, int N) {
    int row = blockIdx.x * blockDim.x + threadIdx.x;
    if (row >= N) return;
    float acc[2 * F_HID];
#pragma unroll
    for (int c = 0; c < 2 * F_HID; ++c) acc[c] = 0.f;

    const float4* xr = (const float4*)(x + (size_t)row * F_IN);
    for (int k4 = 0; k4 < F_IN / 4; ++k4) {
        float4 xv = xr[k4];
        float xs[4] = {xv.x, xv.y, xv.z, xv.w};
#pragma unroll
        for (int j = 0; j < 4; ++j) {
            int k = k4 * 4 + j;
#pragma unroll
            for (int c = 0; c < F_HID; ++c) {
                acc[c]         += xs[j] * Wl[k * F_HID + c];
                acc[F_HID + c] += xs[j] * Wr[k * F_HID + c];
            }
        }
    }
    float4* po = (float4*)(yl + (size_t)row * F_HID);
#pragma unroll
    for (int q = 0; q < F_HID / 4; ++q)
        po[q] = make_float4(acc[4*q], acc[4*q+1], acc[4*q+2], acc[4*q+3]);
    float4* pr = (float4*)(yr + (size_t)row * F_HID);
#pragma unroll
    for (int q = 0; q < F_HID / 4; ++q)
        pr[q] = make_float4(acc[F_HID+4*q], acc[F_HID+4*q+1], acc[F_HID+4*q+2], acc[F_HID+4*q+3]);
}

// ---------------- gather-aggregate layer 1: thread per (node, 4-col group) ----------------
__global__ void k_agg1(const int* __restrict__ rowend, const int* __restrict__ deg,
                       const int* __restrict__ csr, const float* __restrict__ yl,
                       float* __restrict__ agg1, int N) {
    int i = blockIdx.x * blockDim.x + threadIdx.x;
    if (i >= N * 5) return;
    int n = i / 5;
    int cg = i - n * 5;
    int d = deg[n];
    int beg = rowend[n] - d;
    float4 acc = make_float4(0.f, 0.f, 0.f, 0.f);
    for (int j = 0; j < d; ++j) {
        int s = csr[beg + j];
        float4 v = *(const float4*)(yl + (size_t)s * F_HID + cg * 4);
        acc.x += v.x; acc.y += v.y; acc.z += v.z; acc.w += v.w;
    }
    *(float4*)(agg1 + (size_t)n * F_HID + cg * 4) = acc;
}

// ---------------- layer1 epilogue + layer2 projections ----------------
__global__ void k_layer1(const int* __restrict__ deg,
                         const float* __restrict__ agg1,
                         const float* __restrict__ yr,
                         const float* __restrict__ b1,
                         const float* __restrict__ W2l,
                         const float* __restrict__ W2r,
                         float* __restrict__ zl, float* __restrict__ zr, int N) {
    int n = blockIdx.x * blockDim.x + threadIdx.x;
    if (n >= N) return;
    float di = 1.0f / fmaxf((float)deg[n], 1.0f);
    float h[F_HID];
    const float4* pa = (const float4*)(agg1 + (size_t)n * F_HID);
    const float4* pr = (const float4*)(yr + (size_t)n * F_HID);
#pragma unroll
    for (int q = 0; q < F_HID / 4; ++q) {
        float4 a = pa[q];
        float4 r = pr[q];
        h[4*q+0] = fmaxf(a.x * di + b1[4*q+0] + r.x, 0.f);
        h[4*q+1] = fmaxf(a.y * di + b1[4*q+1] + r.y, 0.f);
        h[4*q+2] = fmaxf(a.z * di + b1[4*q+2] + r.z, 0.f);
        h[4*q+3] = fmaxf(a.w * di + b1[4*q+3] + r.w, 0.f);
    }
    float zlo[F_OUT] = {0.f, 0.f, 0.f};
    float zro[F_OUT] = {0.f, 0.f, 0.f};
#pragma unroll
    for (int c = 0; c < F_HID; ++c) {
#pragma unroll
        for (int o = 0; o < F_OUT; ++o) {
            zlo[o] += h[c] * W2l[c * F_OUT + o];
            zro[o] += h[c] * W2r[c * F_OUT + o];
        }
    }
#pragma unroll
    for (int o = 0; o < F_OUT; ++o) {
        zl[(size_t)n * F_OUT + o] = zlo[o];
        zr[(size_t)n * F_OUT + o] = zro[o];
    }
}

// ---------------- gather-aggregate layer 2 + final combine ----------------
__global__ void k_agg2_final(const int* __restrict__ rowend, const int* __restrict__ deg,
                             const int* __restrict__ csr, const float* __restrict__ zl,
                             const float* __restrict__ zr, const float* __restrict__ b2,
                             float* __restrict__ out, int N) {
    int n = blockIdx.x * blockDim.x + threadIdx.x;
    if (n >= N) return;
    int d = deg[n];
    int beg = rowend[n] - d;
    float a0 = 0.f, a1 = 0.f, a2 = 0.f;
    for (int j = 0; j < d; ++j) {
        int s = csr[beg + j];
        const float* z = zl + (size_t)s * F_OUT;
        a0 += z[0]; a1 += z[1]; a2 += z[2];
    }
    float di = 1.0f / fmaxf((float)d, 1.0f);
    out[(size_t)n * F_OUT + 0] = a0 * di + b2[0] + zr[(size_t)n * F_OUT + 0];
    out[(size_t)n * F_OUT + 1] = a1 * di + b2[1] + zr[(size_t)n * F_OUT + 1];
    out[(size_t)n * F_OUT + 2] = a2 * di + b2[2] + zr[(size_t)n * F_OUT + 2];
}

extern "C" void kernel_launch(void* const* d_in, const int* in_sizes, int n_in,
                              void* d_out, int out_size, void* d_ws, size_t ws_size,
                              hipStream_t stream) {
    const float* x   = (const float*)d_in[0];
    const int*   ei  = (const int*)d_in[1];
    const float* W1l = (const float*)d_in[2];
    const float* W1r = (const float*)d_in[3];
    const float* b1  = (const float*)d_in[4];
    const float* W2l = (const float*)d_in[5];
    const float* W2r = (const float*)d_in[6];
    const float* b2  = (const float*)d_in[7];
    float* out = (float*)d_out;

    const int N = in_sizes[0] / F_IN;     // 100000
    const int E = in_sizes[1] / 2;        // 800000
    const int* src = ei;
    const int* dst = ei + E;

    // workspace layout
    int*   wsi      = (int*)d_ws;
    int*   deg      = wsi;                        // N (memset to 0)
    int*   rowstart = deg + N;                    // N
    int*   blocksums= rowstart + N;               // 256
    int*   csr      = blocksums + 256;            // E
    float* yl       = (float*)(csr + E);          // N*20
    float* yr       = yl + (size_t)N * F_HID;     // N*20
    float* agg1     = yr + (size_t)N * F_HID;     // N*20
    float* zl       = agg1 + (size_t)N * F_HID;   // N*3
    float* zr       = zl + (size_t)N * F_OUT;     // N*3

    hipMemsetAsync(deg, 0, (size_t)N * sizeof(int), stream);

    const int B = 256;
    const int NB = (N + 1023) / 1024;   // 98 <= 256
    k_degree    <<<(E + B - 1) / B, B, 0, stream>>>(dst, deg, E);
    k_scan_blk  <<<NB, 256, 0, stream>>>(deg, rowstart, blocksums, N);
    k_scan_sums <<<1, 256, 0, stream>>>(blocksums, NB);
    k_scan_add  <<<(N + B - 1) / B, B, 0, stream>>>(rowstart, blocksums, N);
    k_fill      <<<(E + B - 1) / B, B, 0, stream>>>(src, dst, rowstart, csr, E);
    k_gemm1     <<<(N + B - 1) / B, B, 0, stream>>>(x, W1l, W1r, yl, yr, N);
    k_agg1      <<<(N * 5 + B - 1) / B, B, 0, stream>>>(rowstart, deg, csr, yl, agg1, N);
    k_layer1    <<<(N + B - 1) / B, B, 0, stream>>>(deg, agg1, yr, b1, W2l, W2r, zl, zr, N);
    k_agg2_final<<<(N + B - 1) / B, B, 0, stream>>>(rowstart, deg, csr, zl, zr, b2, out, N);
}